// Round 14
// baseline (413.713 us; speedup 1.0000x reference)
//
#include <hip/hip_runtime.h>

// CacheFuser on MI355X (gfx950) — round 14.
// r13 audit: (a) 88 arch + ~44 AGPR = 132 > 128 -> only 8 waves/CU despite
// 64KB LDS; (b) W L2 traffic = 2MB/block-run (W1 re-read 4x) ~ 116us/dispatch;
// (c) 16 latency-phases + 18 barriers per path-pair.
// Restructure:
//  * Stage ALL 4 sharer tiles (4x16KB) + bf16 HS (16KB) = 80KB = 2 blocks/CU.
//  * Wave's W1 p-slice RESIDENT in 64 regs (loaded once): the 4 align-GEMMs
//    are one 128-MFMA stream, no VMEM, no barriers -> W1 read 1x not 4x.
//  * 5 barriers/path, 4 latency-phases/path.
//  * hsUpd in bf16 (r9-validated precision).
//  * Per-phase register peaks <= ~105 total; plain __launch_bounds__(512).

typedef unsigned int  u32;
typedef unsigned short u16;
typedef __attribute__((ext_vector_type(8))) short bf16x8;   // 8 x bf16
typedef __attribute__((ext_vector_type(4))) float f32x4;

#define LL   8
#define NN   4
#define HH   256
#define RPL  8192            // rows per layer = B*S
#define BM   32              // rows per block
#define ST   (BM * HH)       // 8192 u16 per tile

// d_ws layout: per layer 655360 u16; per matrix: k-tile-major 8192-u16 tiles,
// tile kt holds W^T[p][kt*32..kt*32+32) as [p][32] row-major.
#define LSTRIDE 655360
#define O_AKW1 0
#define O_AKW2 65536
#define O_AVW1 131072
#define O_AVW2 196608
#define O_FKW1 262144        // K=512 -> 16 tiles (0..7 recv half, 8..15 agg half)
#define O_FKW2 393216
#define O_FVW1 458752
#define O_FVW2 589824
// total 5242880 u16 = 10485760 B in d_ws

__device__ __forceinline__ u32 f2bf(float f) {
  u32 u = __builtin_bit_cast(u32, f);
  return (u + 0x7fffu + ((u >> 16) & 1u)) >> 16;   // RNE
}
__device__ __forceinline__ float bf2f(u16 b) {
  u32 u = ((u32)b) << 16;
  return __builtin_bit_cast(float, u);
}
__device__ __forceinline__ float4 ldf4(const float* p) { return *(const float4*)p; }

// ---------------- prep: W[k][p] f32 -> k-tile-major bf16 W^T tiles -----------
__global__ __launch_bounds__(256) void prep_wt_k(
    const float* __restrict__ s0, const float* __restrict__ s1,
    const float* __restrict__ s2, const float* __restrict__ s3,
    const float* __restrict__ s4, const float* __restrict__ s5,
    const float* __restrict__ s6, const float* __restrict__ s7,
    u16* __restrict__ wt)
{
  __shared__ float tile[32][33];
  const int mat = blockIdx.z, l = blockIdx.y, t = blockIdx.x;
  const float* src; int off, K;
  switch (mat) {
    case 0: src = s0; off = O_AKW1; K = 256; break;
    case 1: src = s1; off = O_AKW2; K = 256; break;
    case 2: src = s2; off = O_AVW1; K = 256; break;
    case 3: src = s3; off = O_AVW2; K = 256; break;
    case 4: src = s4; off = O_FKW1; K = 512; break;
    case 5: src = s5; off = O_FKW2; K = 256; break;
    case 6: src = s6; off = O_FVW1; K = 512; break;
    default: src = s7; off = O_FVW2; K = 256; break;
  }
  const int ntk = K >> 5;
  if (t >= ntk * 8) return;                 // 8 p-tiles of 32
  const int tk = t % ntk, tp = t / ntk;
  src += (size_t)l * K * HH;
  u16* dst = wt + (size_t)l * LSTRIDE + off;
  #pragma unroll
  for (int i = 0; i < 4; ++i) {
    int idx = threadIdx.x + i * 256;
    int r = idx >> 5, c = idx & 31;        // r = k-local, c = p-local
    tile[r][c] = src[(size_t)(tk * 32 + r) * HH + tp * 32 + c];
  }
  __syncthreads();
  const int pl = threadIdx.x >> 3, kq = threadIdx.x & 7;
  const int p = tp * 32 + pl;
  ushort4 o;
  o.x = (u16)f2bf(tile[kq * 4 + 0][pl]);
  o.y = (u16)f2bf(tile[kq * 4 + 1][pl]);
  o.z = (u16)f2bf(tile[kq * 4 + 2][pl]);
  o.w = (u16)f2bf(tile[kq * 4 + 3][pl]);
  *(ushort4*)(dst + (size_t)tk * 8192 + p * 32 + kq * 4) = o;
}

// ---------------- main kernel helpers ---------------------------------------
__device__ __forceinline__ void zero22(f32x4 (&a)[2][2]) {
  f32x4 z = {0.f, 0.f, 0.f, 0.f};
  a[0][0] = z; a[0][1] = z; a[1][0] = z; a[1][1] = z;
}

// GEMM with register-resident W slice (no VMEM in loop):
// D[p][q] += Wslice[p][k] * Act[q][k] over K=256.
__device__ __forceinline__ void gemm8R(
    f32x4 (&acc)[2][2], const bf16x8 (&ws)[16],
    const u16* __restrict__ act, int lr, int g)
{
  #pragma unroll
  for (int kt = 0; kt < 8; ++kt) {
    bf16x8 b[2];
    #pragma unroll
    for (int fq = 0; fq < 2; ++fq) {
      int q = fq * 16 + lr;
      int k = (kt * 32 + g * 8) ^ ((q & 7) << 3);
      b[fq] = *(const bf16x8*)(act + q * HH + k);
    }
    #pragma unroll
    for (int fp = 0; fp < 2; ++fp)
      #pragma unroll
      for (int fq = 0; fq < 2; ++fq)
        acc[fp][fq] = __builtin_amdgcn_mfma_f32_16x16x32_bf16(ws[kt * 2 + fp], b[fq], acc[fp][fq], 0, 0, 0);
  }
}

// GEMM streaming W from L2 (4-deep ring); optional fused staging of a
// [32][256] f32 tile (src) -> swizzled bf16 dst.
template<bool STG>
__device__ __forceinline__ void gemm8S(
    f32x4 (&acc)[2][2], const u16* __restrict__ wtile, const u16* __restrict__ act,
    const float* __restrict__ src, u16* __restrict__ dst,
    int tid, int w, int lr, int g)
{
  const u16* wl = wtile + (w * 32 + lr) * 32 + g * 8;   // +fp*512, +kt*8192
  bf16x8 a[4][2];
  #pragma unroll
  for (int c = 0; c < 3; ++c)
    #pragma unroll
    for (int fp = 0; fp < 2; ++fp)
      a[c][fp] = *(const bf16x8*)(wl + c * 8192 + fp * 512);
  __builtin_amdgcn_sched_barrier(0x38F);   // pin prologue a-loads ahead of slots
  float4 slot[4];
  if (STG) {
    #pragma unroll
    for (int c = 0; c < 4; ++c)
      slot[c] = ldf4(src + (size_t)(c * 512 + tid) * 4);
  }
  #pragma unroll
  for (int kt = 0; kt < 8; ++kt) {
    const int cur = kt & 3;
    if (kt < 5) {
      #pragma unroll
      for (int fp = 0; fp < 2; ++fp)
        a[(kt + 3) & 3][fp] = *(const bf16x8*)(wl + (kt + 3) * 8192 + fp * 512);
    }
    bf16x8 b[2];
    #pragma unroll
    for (int fq = 0; fq < 2; ++fq) {
      int q = fq * 16 + lr;
      int k = (kt * 32 + g * 8) ^ ((q & 7) << 3);
      b[fq] = *(const bf16x8*)(act + q * HH + k);
    }
    if (STG && (kt & 1)) {
      const int s = kt >> 1;                // 0..3, compile-time after unroll
      int idx = s * 512 + tid;
      int q = idx >> 6, c = (idx & 63) * 4;
      const float4& v = slot[s];
      ushort4 o;
      o.x = (u16)f2bf(v.x); o.y = (u16)f2bf(v.y);
      o.z = (u16)f2bf(v.z); o.w = (u16)f2bf(v.w);
      *(ushort4*)(dst + q * HH + (c ^ ((q & 7) << 3))) = o;
    }
    #pragma unroll
    for (int fp = 0; fp < 2; ++fp)
      #pragma unroll
      for (int fq = 0; fq < 2; ++fq)
        acc[fp][fq] = __builtin_amdgcn_mfma_f32_16x16x32_bf16(a[cur][fp], b[fq], acc[fp][fq], 0, 0, 0);
  }
}

// Stage all 4 sharer tiles ([32][256] f32 each) -> swizzled bf16 LDS tiles.
// All 16 loads issued before any write (deep HBM pipeline, ~64 transient regs).
__device__ __forceinline__ void stage4(
    u16 (*S)[ST], const float* __restrict__ src, int tid)
{
  float4 v[16];
  #pragma unroll
  for (int i = 0; i < 16; ++i) {
    int n = i >> 2, j = i & 3;
    v[i] = ldf4(src + (size_t)n * RPL * HH + (size_t)(j * 512 + tid) * 4);
  }
  #pragma unroll
  for (int i = 0; i < 16; ++i) {
    int n = i >> 2, j = i & 3;
    int idx = j * 512 + tid;
    int q = idx >> 6, c = (idx & 63) * 4;
    ushort4 o;
    o.x = (u16)f2bf(v[i].x); o.y = (u16)f2bf(v[i].y);
    o.z = (u16)f2bf(v[i].z); o.w = (u16)f2bf(v[i].w);
    *(ushort4*)(&S[n][q * HH + (c ^ ((q & 7) << 3))]) = o;
  }
}

// HS (bf16, owner-exclusive RMW): HS[q][p] (+)= sn * relu(acc + b1)
template<bool INIT>
__device__ __forceinline__ void hsUpd(
    u16* HS, f32x4 (&acc)[2][2], const float* __restrict__ b1,
    float sn, int w, int lr, int g)
{
  #pragma unroll
  for (int fp = 0; fp < 2; ++fp) {
    int p0 = w * 32 + fp * 16 + g * 4;
    float4 bv = *(const float4*)(b1 + p0);
    #pragma unroll
    for (int fq = 0; fq < 2; ++fq) {
      int q = fq * 16 + lr;
      u16* addr = HS + q * HH + (p0 ^ ((q & 7) << 3));
      float v0 = sn * fmaxf(acc[fp][fq][0] + bv.x, 0.f);
      float v1 = sn * fmaxf(acc[fp][fq][1] + bv.y, 0.f);
      float v2 = sn * fmaxf(acc[fp][fq][2] + bv.z, 0.f);
      float v3 = sn * fmaxf(acc[fp][fq][3] + bv.w, 0.f);
      if (!INIT) {
        ushort4 old = *(ushort4*)addr;
        v0 += bf2f(old.x); v1 += bf2f(old.y);
        v2 += bf2f(old.z); v3 += bf2f(old.w);
      }
      ushort4 o;
      o.x = (u16)f2bf(v0); o.y = (u16)f2bf(v1);
      o.z = (u16)f2bf(v2); o.w = (u16)f2bf(v3);
      *(ushort4*)addr = o;
    }
  }
}

// acc -> swizzled bf16 LDS: v = [relu?](acc + bscale*bias)
__device__ __forceinline__ void epiLds(
    u16* buf, f32x4 (&acc)[2][2], const float* __restrict__ bias,
    float bscale, bool doRelu, int w, int lr, int g)
{
  #pragma unroll
  for (int fp = 0; fp < 2; ++fp) {
    int p0 = w * 32 + fp * 16 + g * 4;
    float4 bv = *(const float4*)(bias + p0);
    #pragma unroll
    for (int fq = 0; fq < 2; ++fq) {
      int q = fq * 16 + lr;
      float v0 = acc[fp][fq][0] + bscale * bv.x;
      float v1 = acc[fp][fq][1] + bscale * bv.y;
      float v2 = acc[fp][fq][2] + bscale * bv.z;
      float v3 = acc[fp][fq][3] + bscale * bv.w;
      if (doRelu) {
        v0 = fmaxf(v0, 0.f); v1 = fmaxf(v1, 0.f);
        v2 = fmaxf(v2, 0.f); v3 = fmaxf(v3, 0.f);
      }
      ushort4 o;
      o.x = (u16)f2bf(v0); o.y = (u16)f2bf(v1);
      o.z = (u16)f2bf(v2); o.w = (u16)f2bf(v3);
      *(ushort4*)(buf + q * HH + (p0 ^ ((q & 7) << 3))) = o;
    }
  }
}

// out = recv + gate*(acc + bias)
__device__ __forceinline__ void epiOut(
    f32x4 (&acc)[2][2], const float* __restrict__ bias,
    const float* __restrict__ recv, float* __restrict__ outp,
    float gate, int w, int lr, int g)
{
  #pragma unroll
  for (int fp = 0; fp < 2; ++fp) {
    int p0 = w * 32 + fp * 16 + g * 4;
    float4 bv = *(const float4*)(bias + p0);
    #pragma unroll
    for (int fq = 0; fq < 2; ++fq) {
      int q = fq * 16 + lr;
      float4 rv = *(const float4*)(recv + (size_t)q * HH + p0);
      float4 ov;
      ov.x = rv.x + gate * (acc[fp][fq][0] + bv.x);
      ov.y = rv.y + gate * (acc[fp][fq][1] + bv.y);
      ov.z = rv.z + gate * (acc[fp][fq][2] + bv.z);
      ov.w = rv.w + gate * (acc[fp][fq][3] + bv.w);
      *(float4*)(outp + (size_t)q * HH + p0) = ov;
    }
  }
}

__global__ __launch_bounds__(512) void CacheFuser_73873437491748_kernel(
    const float* __restrict__ recv_k, const float* __restrict__ recv_v,
    const float* __restrict__ shar_k, const float* __restrict__ shar_v,
    const float* __restrict__ ew, const float* __restrict__ alpha,
    const float* __restrict__ ak_b1, const float* __restrict__ ak_b2,
    const float* __restrict__ av_b1, const float* __restrict__ av_b2,
    const float* __restrict__ fk_b1, const float* __restrict__ fk_b2,
    const float* __restrict__ fv_b1, const float* __restrict__ fv_b2,
    const u16* __restrict__ wt, float* __restrict__ out)
{
  __shared__ u16 S[4][ST];     // 4 x 16 KB sharer tiles (later: recv/agg/hidden)
  __shared__ u16 HS[ST];       // 16 KB bf16 hidden-sum
  // total 80 KB -> exactly 2 blocks/CU (needs total regs <= 128)

  const int bid = blockIdx.x;
  const int l = bid & 7, t = bid >> 3;          // layer <-> XCD affinity
  const int tid = threadIdx.x;
  const int w = tid >> 6, lane = tid & 63, lr = lane & 15, g = lane >> 4;

  const size_t row0 = (size_t)t * BM;
  const u16* lw = wt + (size_t)l * LSTRIDE;
  const float gate = 1.f / (1.f + __expf(-2.f * alpha[l]));
  const float* ewl = ew + l * NN;

  #pragma unroll 1
  for (int path = 0; path < 2; ++path) {
    const float* recvB = (path ? recv_v : recv_k) + ((size_t)l * RPL + row0) * HH;
    const float* sharB = (path ? shar_v : shar_k) + ((size_t)l * NN * RPL + row0) * HH;
    const u16* W1  = lw + (path ? O_AVW1 : O_AKW1);
    const u16* W2  = lw + (path ? O_AVW2 : O_AKW2);
    const u16* FW1 = lw + (path ? O_FVW1 : O_FKW1);
    const u16* FW2 = lw + (path ? O_FVW2 : O_FKW2);
    const float* b1  = (path ? av_b1 : ak_b1) + l * HH;
    const float* b2  = (path ? av_b2 : ak_b2) + l * HH;
    const float* fb1 = (path ? fv_b1 : fk_b1) + l * HH;
    const float* fb2 = (path ? fv_b2 : fk_b2) + l * HH;
    float* outp = out + ((size_t)(path * LL + l) * RPL + row0) * HH;

    // ---- phase A: stage all 4 sharer tiles -------------------------------
    stage4(S, sharB, tid);
    __syncthreads();

    // ---- phase B: W1-resident align GEMMs (no VMEM, no barriers) ---------
    bf16x8 ws[16];
    {
      const u16* wl = W1 + (w * 32 + lr) * 32 + g * 8;
      #pragma unroll
      for (int kt = 0; kt < 8; ++kt)
        #pragma unroll
        for (int fp = 0; fp < 2; ++fp)
          ws[kt * 2 + fp] = *(const bf16x8*)(wl + kt * 8192 + fp * 512);
    }
    float sS = 0.f;
    #pragma unroll 1
    for (int n = 0; n < NN; ++n) {
      float sn = ewl[n] * 0.25f; sS += sn;
      f32x4 h[2][2]; zero22(h);
      gemm8R(h, ws, &S[n][0], lr, g);
      if (n == 0) hsUpd<true >(HS, h, b1, sn, w, lr, g);
      else        hsUpd<false>(HS, h, b1, sn, w, lr, g);
    }
    __syncthreads();                           // HS complete; S[0..3] free

    // ---- phase C: agg GEMM (W2 from L2) + stage recv -> S0 ---------------
    f32x4 agg[2][2]; zero22(agg);
    gemm8S<true>(agg, W2, HS, recvB, &S[0][0], tid, w, lr, g);
    epiLds(&S[1][0], agg, b2, sS, false, w, lr, g);   // S1 = agg + sS*b2
    __syncthreads();                           // S0 = recv, S1 = agg ready

    // ---- phase D: fuse hidden --------------------------------------------
    f32x4 h2[2][2]; zero22(h2);
    gemm8S<false>(h2, FW1, &S[0][0], nullptr, nullptr, tid, w, lr, g);            // recv half
    gemm8S<false>(h2, FW1 + 8 * 8192, &S[1][0], nullptr, nullptr, tid, w, lr, g); // agg half
    epiLds(&S[2][0], h2, fb1, 1.f, true, w, lr, g);   // S2 = fuse hidden
    __syncthreads();                           // S2 ready

    // ---- phase E: delta GEMM + gated output ------------------------------
    f32x4 dd[2][2]; zero22(dd);
    gemm8S<false>(dd, FW2, &S[2][0], nullptr, nullptr, tid, w, lr, g);
    epiOut(dd, fb2, recvB, outp, gate, w, lr, g);
    __syncthreads();                           // S free for next path's stage4
  }
}

extern "C" void kernel_launch(void* const* d_in, const int* in_sizes, int n_in,
                              void* d_out, int out_size, void* d_ws, size_t ws_size,
                              hipStream_t stream)
{
  const float* recv_k = (const float*)d_in[0];
  const float* recv_v = (const float*)d_in[1];
  const float* shar_k = (const float*)d_in[2];
  const float* shar_v = (const float*)d_in[3];
  const float* ew     = (const float*)d_in[4];
  const float* alpha  = (const float*)d_in[5];
  const float* ak_w1 = (const float*)d_in[6];  const float* ak_b1 = (const float*)d_in[7];
  const float* ak_w2 = (const float*)d_in[8];  const float* ak_b2 = (const float*)d_in[9];
  const float* av_w1 = (const float*)d_in[10]; const float* av_b1 = (const float*)d_in[11];
  const float* av_w2 = (const float*)d_in[12]; const float* av_b2 = (const float*)d_in[13];
  const float* fk_w1 = (const float*)d_in[14]; const float* fk_b1 = (const float*)d_in[15];
  const float* fk_w2 = (const float*)d_in[16]; const float* fk_b2 = (const float*)d_in[17];
  const float* fv_w1 = (const float*)d_in[18]; const float* fv_b1 = (const float*)d_in[19];
  const float* fv_w2 = (const float*)d_in[20]; const float* fv_b2 = (const float*)d_in[21];
  u16* wtw = (u16*)d_ws;          // 10485760 B
  float* outp = (float*)d_out;

  prep_wt_k<<<dim3(128, 8, 8), dim3(256), 0, stream>>>(
      ak_w1, ak_w2, av_w1, av_w2, fk_w1, fk_w2, fv_w1, fv_w2, wtw);

  CacheFuser_73873437491748_kernel<<<dim3(2048), dim3(512), 0, stream>>>(
      recv_k, recv_v, shar_k, shar_v, ew, alpha,
      ak_b1, ak_b2, av_b1, av_b2, fk_b1, fk_b2, fv_b1, fv_b2, wtw, outp);
}

// Round 15
// 266.343 us; speedup vs baseline: 1.5533x; 1.5533x over previous
//
#include <hip/hip_runtime.h>

// CacheFuser on MI355X (gfx950) — round 15.
// Per-SIMD MFMA arithmetic: 16x16x32 ~ 19.4 cy/SIMD -> 66us floor at ANY
// occupancy. r13 (365us, best) idles 80%: BM=32 phases hold only ~1240cy of
// MFMA/SIMD against a fixed latency ramp per barrier-phase.
// r15: BM=64 at 1 block/CU -> 2 waves/SIMD -> 256-reg budget. That budget
// funds W1-RESIDENT GEMM1 (64 regs, W read once/block, zero VMEM in phase B)
// with staging still FUSED into compute (r14's naked-stage mistake avoided).
// Wave tile 32p x 64q (acc[2][4] AGPR); streamed GEMMs keep the 4-deep ring.
// Phases halve, MFMA/phase doubles. LDS 32+32+64 = 128KB.

typedef unsigned int  u32;
typedef unsigned short u16;
typedef __attribute__((ext_vector_type(8))) short bf16x8;   // 8 x bf16
typedef __attribute__((ext_vector_type(4))) float f32x4;

#define LL   8
#define NN   4
#define HH   256
#define RPL  8192            // rows per layer = B*S
#define BM   64              // rows per block
#define ST   (BM * HH)       // 16384 u16 per tile (32 KB)

// d_ws layout: per layer 655360 u16; per matrix: k-tile-major 8192-u16 tiles,
// tile kt holds W^T[p][kt*32..kt*32+32) as [p][32] row-major.
#define LSTRIDE 655360
#define O_AKW1 0
#define O_AKW2 65536
#define O_AVW1 131072
#define O_AVW2 196608
#define O_FKW1 262144        // K=512 -> 16 tiles (0..7 recv half, 8..15 agg half)
#define O_FKW2 393216
#define O_FVW1 458752
#define O_FVW2 589824
// total 5242880 u16 = 10485760 B in d_ws

__device__ __forceinline__ u32 f2bf(float f) {
  u32 u = __builtin_bit_cast(u32, f);
  return (u + 0x7fffu + ((u >> 16) & 1u)) >> 16;   // RNE
}
__device__ __forceinline__ float4 ldf4(const float* p) { return *(const float4*)p; }

// ---------------- prep: W[k][p] f32 -> k-tile-major bf16 W^T tiles -----------
__global__ __launch_bounds__(256) void prep_wt_k(
    const float* __restrict__ s0, const float* __restrict__ s1,
    const float* __restrict__ s2, const float* __restrict__ s3,
    const float* __restrict__ s4, const float* __restrict__ s5,
    const float* __restrict__ s6, const float* __restrict__ s7,
    u16* __restrict__ wt)
{
  __shared__ float tile[32][33];
  const int mat = blockIdx.z, l = blockIdx.y, t = blockIdx.x;
  const float* src; int off, K;
  switch (mat) {
    case 0: src = s0; off = O_AKW1; K = 256; break;
    case 1: src = s1; off = O_AKW2; K = 256; break;
    case 2: src = s2; off = O_AVW1; K = 256; break;
    case 3: src = s3; off = O_AVW2; K = 256; break;
    case 4: src = s4; off = O_FKW1; K = 512; break;
    case 5: src = s5; off = O_FKW2; K = 256; break;
    case 6: src = s6; off = O_FVW1; K = 512; break;
    default: src = s7; off = O_FVW2; K = 256; break;
  }
  const int ntk = K >> 5;
  if (t >= ntk * 8) return;                 // 8 p-tiles of 32
  const int tk = t % ntk, tp = t / ntk;
  src += (size_t)l * K * HH;
  u16* dst = wt + (size_t)l * LSTRIDE + off;
  #pragma unroll
  for (int i = 0; i < 4; ++i) {
    int idx = threadIdx.x + i * 256;
    int r = idx >> 5, c = idx & 31;        // r = k-local, c = p-local
    tile[r][c] = src[(size_t)(tk * 32 + r) * HH + tp * 32 + c];
  }
  __syncthreads();
  const int pl = threadIdx.x >> 3, kq = threadIdx.x & 7;
  const int p = tp * 32 + pl;
  ushort4 o;
  o.x = (u16)f2bf(tile[kq * 4 + 0][pl]);
  o.y = (u16)f2bf(tile[kq * 4 + 1][pl]);
  o.z = (u16)f2bf(tile[kq * 4 + 2][pl]);
  o.w = (u16)f2bf(tile[kq * 4 + 3][pl]);
  *(ushort4*)(dst + (size_t)tk * 8192 + p * 32 + kq * 4) = o;
}

// ---------------- main kernel helpers ---------------------------------------
__device__ __forceinline__ void zero24(f32x4 (&a)[2][4]) {
  f32x4 z = {0.f, 0.f, 0.f, 0.f};
  #pragma unroll
  for (int i = 0; i < 2; ++i)
    #pragma unroll
    for (int j = 0; j < 4; ++j) a[i][j] = z;
}

// GEMM with register-resident W slice; optional fused staging of a
// [64][256] f32 tile (src) -> swizzled bf16 dst (one 8-row chunk per kt,
// 4-deep slot ring).
template<bool STG>
__device__ __forceinline__ void gemm8R(
    f32x4 (&acc)[2][4], const bf16x8 (&ws)[16], const u16* __restrict__ act,
    const float* __restrict__ src, u16* __restrict__ dst,
    int tid, int lr, int g)
{
  float4 slot[4];
  if (STG) {
    #pragma unroll
    for (int c = 0; c < 4; ++c)
      slot[c] = ldf4(src + (size_t)(c * 512 + tid) * 4);
  }
  #pragma unroll
  for (int kt = 0; kt < 8; ++kt) {
    bf16x8 b[4];
    #pragma unroll
    for (int fq = 0; fq < 4; ++fq) {
      int q = fq * 16 + lr;
      int k = (kt * 32 + g * 8) ^ ((q & 7) << 3);
      b[fq] = *(const bf16x8*)(act + q * HH + k);
    }
    if (STG) {
      const int s = kt & 3;
      int idx = kt * 512 + tid;
      int q = idx >> 6, c = (idx & 63) * 4;
      const float4& v = slot[s];
      ushort4 o;
      o.x = (u16)f2bf(v.x); o.y = (u16)f2bf(v.y);
      o.z = (u16)f2bf(v.z); o.w = (u16)f2bf(v.w);
      *(ushort4*)(dst + q * HH + (c ^ ((q & 7) << 3))) = o;
      if (kt + 4 < 8)
        slot[s] = ldf4(src + (size_t)((kt + 4) * 512 + tid) * 4);
    }
    #pragma unroll
    for (int fp = 0; fp < 2; ++fp)
      #pragma unroll
      for (int fq = 0; fq < 4; ++fq)
        acc[fp][fq] = __builtin_amdgcn_mfma_f32_16x16x32_bf16(ws[kt * 2 + fp], b[fq], acc[fp][fq], 0, 0, 0);
  }
}

// GEMM streaming W from L2 (4-deep a-ring); optional fused staging as above.
template<bool STG>
__device__ __forceinline__ void gemm8S(
    f32x4 (&acc)[2][4], const u16* __restrict__ wtile, const u16* __restrict__ act,
    const float* __restrict__ src, u16* __restrict__ dst,
    int tid, int w, int lr, int g)
{
  const u16* wl = wtile + (w * 32 + lr) * 32 + g * 8;   // +fp*512, +kt*8192
  bf16x8 a[4][2];
  #pragma unroll
  for (int c = 0; c < 3; ++c)
    #pragma unroll
    for (int fp = 0; fp < 2; ++fp)
      a[c][fp] = *(const bf16x8*)(wl + c * 8192 + fp * 512);
  __builtin_amdgcn_sched_barrier(0x38F);   // pin prologue a-loads ahead of slots
  float4 slot[4];
  if (STG) {
    #pragma unroll
    for (int c = 0; c < 4; ++c)
      slot[c] = ldf4(src + (size_t)(c * 512 + tid) * 4);
  }
  #pragma unroll
  for (int kt = 0; kt < 8; ++kt) {
    const int cur = kt & 3;
    if (kt < 5) {
      #pragma unroll
      for (int fp = 0; fp < 2; ++fp)
        a[(kt + 3) & 3][fp] = *(const bf16x8*)(wl + (kt + 3) * 8192 + fp * 512);
    }
    bf16x8 b[4];
    #pragma unroll
    for (int fq = 0; fq < 4; ++fq) {
      int q = fq * 16 + lr;
      int k = (kt * 32 + g * 8) ^ ((q & 7) << 3);
      b[fq] = *(const bf16x8*)(act + q * HH + k);
    }
    if (STG) {
      const int s = kt & 3;
      int idx = kt * 512 + tid;
      int q = idx >> 6, c = (idx & 63) * 4;
      const float4& v = slot[s];
      ushort4 o;
      o.x = (u16)f2bf(v.x); o.y = (u16)f2bf(v.y);
      o.z = (u16)f2bf(v.z); o.w = (u16)f2bf(v.w);
      *(ushort4*)(dst + q * HH + (c ^ ((q & 7) << 3))) = o;
      if (kt + 4 < 8)
        slot[s] = ldf4(src + (size_t)((kt + 4) * 512 + tid) * 4);
    }
    #pragma unroll
    for (int fp = 0; fp < 2; ++fp)
      #pragma unroll
      for (int fq = 0; fq < 4; ++fq)
        acc[fp][fq] = __builtin_amdgcn_mfma_f32_16x16x32_bf16(a[cur][fp], b[fq], acc[fp][fq], 0, 0, 0);
  }
}

// One-shot staging: [64][256] f32 -> swizzled bf16 LDS.
__device__ __forceinline__ void stageDirect(u16* dst, const float* __restrict__ src, int tid) {
  #pragma unroll
  for (int i = 0; i < 8; ++i) {
    int idx = i * 512 + tid;
    float4 v = ldf4(src + (size_t)idx * 4);
    int q = idx >> 6, c = (idx & 63) * 4;
    ushort4 o;
    o.x = (u16)f2bf(v.x); o.y = (u16)f2bf(v.y);
    o.z = (u16)f2bf(v.z); o.w = (u16)f2bf(v.w);
    *(ushort4*)(dst + q * HH + (c ^ ((q & 7) << 3))) = o;
  }
}

// HF (f32, owner-exclusive RMW): HF[q][p] (+)= sn * relu(acc + b1)
template<bool INIT>
__device__ __forceinline__ void hsUpd(
    float* HF, f32x4 (&acc)[2][4], const float* __restrict__ b1,
    float sn, int w, int lr, int g)
{
  #pragma unroll
  for (int fp = 0; fp < 2; ++fp) {
    int p0 = w * 32 + fp * 16 + g * 4;
    float4 bv = *(const float4*)(b1 + p0);
    #pragma unroll
    for (int fq = 0; fq < 4; ++fq) {
      int q = fq * 16 + lr;
      float* addr = HF + q * HH + (p0 ^ ((q & 7) << 3));
      float4 nv;
      nv.x = sn * fmaxf(acc[fp][fq][0] + bv.x, 0.f);
      nv.y = sn * fmaxf(acc[fp][fq][1] + bv.y, 0.f);
      nv.z = sn * fmaxf(acc[fp][fq][2] + bv.z, 0.f);
      nv.w = sn * fmaxf(acc[fp][fq][3] + bv.w, 0.f);
      if (!INIT) {
        float4 old = *(float4*)addr;
        nv.x += old.x; nv.y += old.y; nv.z += old.z; nv.w += old.w;
      }
      *(float4*)addr = nv;
    }
  }
}

// convert HF (f32 [64][256], swizzled) -> bf16 tile (same swizzle)
__device__ __forceinline__ void convertHS(const float* __restrict__ HF, u16* dst, int tid) {
  #pragma unroll
  for (int j = 0; j < 8; ++j) {
    int idx = j * 512 + tid;
    int q = idx >> 6, c = (idx & 63) * 4;
    int sw = c ^ ((q & 7) << 3);
    float4 v = *(const float4*)(HF + q * HH + sw);
    ushort4 o;
    o.x = (u16)f2bf(v.x); o.y = (u16)f2bf(v.y);
    o.z = (u16)f2bf(v.z); o.w = (u16)f2bf(v.w);
    *(ushort4*)(dst + q * HH + sw) = o;
  }
}

// acc -> swizzled bf16 LDS: v = [relu?](acc + bscale*bias)
__device__ __forceinline__ void epiLds(
    u16* buf, f32x4 (&acc)[2][4], const float* __restrict__ bias,
    float bscale, bool doRelu, int w, int lr, int g)
{
  #pragma unroll
  for (int fp = 0; fp < 2; ++fp) {
    int p0 = w * 32 + fp * 16 + g * 4;
    float4 bv = *(const float4*)(bias + p0);
    #pragma unroll
    for (int fq = 0; fq < 4; ++fq) {
      int q = fq * 16 + lr;
      float v0 = acc[fp][fq][0] + bscale * bv.x;
      float v1 = acc[fp][fq][1] + bscale * bv.y;
      float v2 = acc[fp][fq][2] + bscale * bv.z;
      float v3 = acc[fp][fq][3] + bscale * bv.w;
      if (doRelu) {
        v0 = fmaxf(v0, 0.f); v1 = fmaxf(v1, 0.f);
        v2 = fmaxf(v2, 0.f); v3 = fmaxf(v3, 0.f);
      }
      ushort4 o;
      o.x = (u16)f2bf(v0); o.y = (u16)f2bf(v1);
      o.z = (u16)f2bf(v2); o.w = (u16)f2bf(v3);
      *(ushort4*)(buf + q * HH + (p0 ^ ((q & 7) << 3))) = o;
    }
  }
}

// out = recv + gate*(acc + bias)
__device__ __forceinline__ void epiOut(
    f32x4 (&acc)[2][4], const float* __restrict__ bias,
    const float* __restrict__ recv, float* __restrict__ outp,
    float gate, int w, int lr, int g)
{
  #pragma unroll
  for (int fp = 0; fp < 2; ++fp) {
    int p0 = w * 32 + fp * 16 + g * 4;
    float4 bv = *(const float4*)(bias + p0);
    #pragma unroll
    for (int fq = 0; fq < 4; ++fq) {
      int q = fq * 16 + lr;
      float4 rv = *(const float4*)(recv + (size_t)q * HH + p0);
      float4 ov;
      ov.x = rv.x + gate * (acc[fp][fq][0] + bv.x);
      ov.y = rv.y + gate * (acc[fp][fq][1] + bv.y);
      ov.z = rv.z + gate * (acc[fp][fq][2] + bv.z);
      ov.w = rv.w + gate * (acc[fp][fq][3] + bv.w);
      *(float4*)(outp + (size_t)q * HH + p0) = ov;
    }
  }
}

__global__ __launch_bounds__(512) void CacheFuser_73873437491748_kernel(
    const float* __restrict__ recv_k, const float* __restrict__ recv_v,
    const float* __restrict__ shar_k, const float* __restrict__ shar_v,
    const float* __restrict__ ew, const float* __restrict__ alpha,
    const float* __restrict__ ak_b1, const float* __restrict__ ak_b2,
    const float* __restrict__ av_b1, const float* __restrict__ av_b2,
    const float* __restrict__ fk_b1, const float* __restrict__ fk_b2,
    const float* __restrict__ fv_b1, const float* __restrict__ fv_b2,
    const u16* __restrict__ wt, float* __restrict__ out)
{
  __shared__ u16 XA[ST];        // 32 KB input ping (swizzled bf16)
  __shared__ u16 XB[ST];        // 32 KB input pong
  __shared__ float HF[ST];      // 64 KB f32 hidden-sum; later 2x bf16 scratch
  // total 128 KB -> 1 block/CU, 2 waves/SIMD -> 256-reg budget (no spill risk)

  const int bid = blockIdx.x;
  const int l = bid & 7, t = bid >> 3;          // layer <-> XCD affinity
  const int tid = threadIdx.x;
  const int w = tid >> 6, lane = tid & 63, lr = lane & 15, g = lane >> 4;

  u16* F0 = (u16*)HF;            // bf16 scratch 0 (agg tile, 32 KB)
  u16* F1 = (u16*)HF + ST;       // bf16 scratch 1 (fuse-hidden tile, 32 KB)

  const size_t row0 = (size_t)t * BM;
  const u16* lw = wt + (size_t)l * LSTRIDE;
  const float gate = 1.f / (1.f + __expf(-2.f * alpha[l]));
  const float* ewl = ew + l * NN;

  stageDirect(XA, shar_k + ((size_t)l * NN * RPL + row0) * HH, tid);  // K sharer0

  #pragma unroll 1
  for (int path = 0; path < 2; ++path) {
    const float* recvB = (path ? recv_v : recv_k) + ((size_t)l * RPL + row0) * HH;
    const float* sharB = (path ? shar_v : shar_k) + ((size_t)l * NN * RPL + row0) * HH;
    const u16* W1  = lw + (path ? O_AVW1 : O_AKW1);
    const u16* W2  = lw + (path ? O_AVW2 : O_AKW2);
    const u16* FW1 = lw + (path ? O_FVW1 : O_FKW1);
    const u16* FW2 = lw + (path ? O_FVW2 : O_FKW2);
    const float* b1  = (path ? av_b1 : ak_b1) + l * HH;
    const float* b2  = (path ? av_b2 : ak_b2) + l * HH;
    const float* fb1 = (path ? fv_b1 : fk_b1) + l * HH;
    const float* fb2 = (path ? fv_b2 : fk_b2) + l * HH;
    float* outp = out + ((size_t)(path * LL + l) * RPL + row0) * HH;

    // W1 p-slice resident (16 x bf16x8 = 64 regs, read from L2 once/path)
    bf16x8 ws[16];
    {
      const u16* wl = W1 + (w * 32 + lr) * 32 + g * 8;
      #pragma unroll
      for (int kt = 0; kt < 8; ++kt)
        #pragma unroll
        for (int fp = 0; fp < 2; ++fp)
          ws[kt * 2 + fp] = *(const bf16x8*)(wl + kt * 8192 + fp * 512);
    }

    int cur = path;
    float sS = 0.f;

    #pragma unroll 1
    for (int n = 0; n < NN; ++n) {
      float sn = ewl[n] * 0.25f; sS += sn;
      __syncthreads();                         // input n ready in cur buffer
      u16* XC = cur ? XB : XA;
      u16* XO = cur ? XA : XB;
      const float* nsrc = (n < 3) ? sharB + (size_t)(n + 1) * RPL * HH : recvB;
      f32x4 h[2][4]; zero24(h);
      gemm8R<true>(h, ws, XC, nsrc, XO, tid, lr, g);   // W-resident + fused stage
      if (n == 0) hsUpd<true >(HF, h, b1, sn, w, lr, g);
      else        hsUpd<false>(HF, h, b1, sn, w, lr, g);
      cur ^= 1;
    }
    // after loop: recv in cur buffer, cur^1 dead (last sharer)
    u16* XR = cur ? XB : XA;
    u16* XD = cur ? XA : XB;
    __syncthreads();                           // HF complete; recv staged
    convertHS(HF, XD, tid);                    // XD = bf16(hsum)
    __syncthreads();
    f32x4 agg[2][4]; zero24(agg);
    gemm8S<false>(agg, W2, XD, nullptr, nullptr, tid, w, lr, g);
    epiLds(F0, agg, b2, sS, false, w, lr, g);  // F0 = agg + sS*b2 (HF f32 dead)
    __syncthreads();                           // F0 ready; XD reads done
    f32x4 h2[2][4]; zero24(h2);
    if (path == 0) {
      // fuse GEMM1 (recv half) while streaming V-path sharer0 -> XD
      gemm8S<true>(h2, FW1, XR, shar_v + ((size_t)l * NN * RPL + row0) * HH, XD,
                   tid, w, lr, g);
    } else {
      gemm8S<false>(h2, FW1, XR, nullptr, nullptr, tid, w, lr, g);
    }
    gemm8S<false>(h2, FW1 + 8 * 8192, F0, nullptr, nullptr, tid, w, lr, g);  // agg half
    epiLds(F1, h2, fb1, 1.f, true, w, lr, g);  // F1 = fuse hidden (disjoint from F0)
    __syncthreads();                           // F1 ready
    f32x4 dd[2][4]; zero24(dd);
    gemm8S<false>(dd, FW2, F1, nullptr, nullptr, tid, w, lr, g);
    epiOut(dd, fb2, recvB, outp, gate, w, lr, g);
    // path1 input (V sharer0) sits in XD; after cur^=1 the loop reads it.
    cur ^= 1;
  }
}

extern "C" void kernel_launch(void* const* d_in, const int* in_sizes, int n_in,
                              void* d_out, int out_size, void* d_ws, size_t ws_size,
                              hipStream_t stream)
{
  const float* recv_k = (const float*)d_in[0];
  const float* recv_v = (const float*)d_in[1];
  const float* shar_k = (const float*)d_in[2];
  const float* shar_v = (const float*)d_in[3];
  const float* ew     = (const float*)d_in[4];
  const float* alpha  = (const float*)d_in[5];
  const float* ak_w1 = (const float*)d_in[6];  const float* ak_b1 = (const float*)d_in[7];
  const float* ak_w2 = (const float*)d_in[8];  const float* ak_b2 = (const float*)d_in[9];
  const float* av_w1 = (const float*)d_in[10]; const float* av_b1 = (const float*)d_in[11];
  const float* av_w2 = (const float*)d_in[12]; const float* av_b2 = (const float*)d_in[13];
  const float* fk_w1 = (const float*)d_in[14]; const float* fk_b1 = (const float*)d_in[15];
  const float* fk_w2 = (const float*)d_in[16]; const float* fk_b2 = (const float*)d_in[17];
  const float* fv_w1 = (const float*)d_in[18]; const float* fv_b1 = (const float*)d_in[19];
  const float* fv_w2 = (const float*)d_in[20]; const float* fv_b2 = (const float*)d_in[21];
  u16* wtw = (u16*)d_ws;          // 10485760 B
  float* outp = (float*)d_out;

  prep_wt_k<<<dim3(128, 8, 8), dim3(256), 0, stream>>>(
      ak_w1, ak_w2, av_w1, av_w2, fk_w1, fk_w2, fv_w1, fv_w2, wtw);

  CacheFuser_73873437491748_kernel<<<dim3(1024), dim3(512), 0, stream>>>(
      recv_k, recv_v, shar_k, shar_v, ew, alpha,
      ak_b1, ak_b2, av_b1, av_b2, fk_b1, fk_b2, fv_b1, fv_b2, wtw, outp);
}